// Round 1
// baseline (223.423 us; speedup 1.0000x reference)
//
#include <hip/hip_runtime.h>

// Problem constants
#define S_DIM 8192
#define K_DIM 1024
#define RO_DIM 4096
#define O_DIM 64
#define SO (S_DIM * O_DIM)

typedef __attribute__((ext_vector_type(8))) __bf16 bf16x8;
typedef __attribute__((ext_vector_type(4))) float floatx4;
typedef __attribute__((ext_vector_type(4))) unsigned short ushx4;

__device__ inline unsigned short f2bf(float f) {
  unsigned u = __builtin_bit_cast(unsigned, f);
  u += 0x7fff + ((u >> 16) & 1);  // round-to-nearest-even
  return (unsigned short)(u >> 16);
}

// ---------------------------------------------------------------- cast X,W -> bf16
__global__ __launch_bounds__(256) void cast_kernel(const float* __restrict__ X,
                                                   const float* __restrict__ W,
                                                   unsigned short* __restrict__ Xb,
                                                   unsigned short* __restrict__ Wb) {
  int i = blockIdx.x * 256 + threadIdx.x;
  const int NX4 = (S_DIM * K_DIM) / 4;
  float4 v;
  unsigned short* dst;
  if (i < NX4) {
    v = ((const float4*)X)[i];
    dst = Xb + (size_t)i * 4;
  } else {
    int j = i - NX4;
    v = ((const float4*)W)[j];
    dst = Wb + (size_t)j * 4;
  }
  ushx4 o;
  o.x = f2bf(v.x); o.y = f2bf(v.y); o.z = f2bf(v.z); o.w = f2bf(v.w);
  *(ushx4*)dst = o;
}

// ---------------------------------------------------------------- fused GEMM+sigmoid+rule-reduce
// 128x128 tile, BK=32, 4 waves of 4x4 16x16x32 MFMA fragments.
// Epilogue: z += bias; h = sigmoid(z); ypart[row][o] (LDS) accumulates
// lambda[s, rule] * h over the tile's 2 rule blocks; one fp32 partial slice
// per N-tile written to workspace (reduced by reduce_kernel).
__global__ __launch_bounds__(256) void gemm_kernel(const unsigned short* __restrict__ Xb,
                                                   const unsigned short* __restrict__ Wb,
                                                   const float* __restrict__ bias,
                                                   const float* __restrict__ lam,
                                                   float* __restrict__ partial) {
  __shared__ unsigned short Atile[128 * 32];  // 8 KB, [row][k] contiguous (global_load_lds order)
  __shared__ unsigned short Btile[128 * 32];  // 8 KB
  __shared__ float ypart[128 * O_DIM];        // 32 KB

  const int t = threadIdx.x;
  const int lane = t & 63;
  const int w = t >> 6;
  const int wm = w & 1;        // wave row half (rows wm*64..+63)
  const int wn = w >> 1;       // wave col half (cols wn*64..+63) == rule within tile
  const int quad = lane >> 4;  // 0..3
  const int l16 = lane & 15;
  const int gm0 = blockIdx.y * 128;
  const int gn0 = blockIdx.x * 128;

  floatx4 acc[4][4];
#pragma unroll
  for (int mi = 0; mi < 4; ++mi)
#pragma unroll
    for (int ni = 0; ni < 4; ++ni) acc[mi][ni] = (floatx4){0.f, 0.f, 0.f, 0.f};

  for (int k0 = 0; k0 < K_DIM; k0 += 32) {
    __syncthreads();
#pragma unroll
    for (int i = 0; i < 2; ++i) {
      int idx = i * 256 + t;       // 0..511, lane-contiguous within each wave
      int row = idx >> 2;          // tile row 0..127
      int cc = idx & 3;            // 8-elem chunk within BK=32
      const unsigned short* ga = Xb + (size_t)(gm0 + row) * K_DIM + k0 + cc * 8;
      const unsigned short* gb = Wb + (size_t)(gn0 + row) * K_DIM + k0 + cc * 8;
      __builtin_amdgcn_global_load_lds(
          (const __attribute__((address_space(1))) void*)ga,
          (__attribute__((address_space(3))) void*)(Atile + idx * 8), 16, 0, 0);
      __builtin_amdgcn_global_load_lds(
          (const __attribute__((address_space(1))) void*)gb,
          (__attribute__((address_space(3))) void*)(Btile + idx * 8), 16, 0, 0);
    }
    __syncthreads();

    bf16x8 af[4], bfr[4];
#pragma unroll
    for (int mi = 0; mi < 4; ++mi)
      af[mi] = *(const bf16x8*)(Atile + (wm * 64 + mi * 16 + l16) * 32 + quad * 8);
#pragma unroll
    for (int ni = 0; ni < 4; ++ni)
      bfr[ni] = *(const bf16x8*)(Btile + (wn * 64 + ni * 16 + l16) * 32 + quad * 8);
#pragma unroll
    for (int mi = 0; mi < 4; ++mi)
#pragma unroll
      for (int ni = 0; ni < 4; ++ni)
        acc[mi][ni] = __builtin_amdgcn_mfma_f32_16x16x32_bf16(af[mi], bfr[ni], acc[mi][ni], 0, 0, 0);
  }

  // ---- epilogue ----
  const int rule = blockIdx.x * 2 + wn;
  float bv[4];
#pragma unroll
  for (int ni = 0; ni < 4; ++ni) bv[ni] = bias[gn0 + wn * 64 + ni * 16 + l16];

  __syncthreads();
  if (wn == 0) {
#pragma unroll
    for (int mi = 0; mi < 4; ++mi) {
#pragma unroll
      for (int reg = 0; reg < 4; ++reg) {
        int row = wm * 64 + mi * 16 + quad * 4 + reg;
        float lv = lam[(size_t)(gm0 + row) * 64 + rule];
#pragma unroll
        for (int ni = 0; ni < 4; ++ni) {
          float z = acc[mi][ni][reg] + bv[ni];
          float h = 1.f / (1.f + __expf(-z));
          ypart[row * O_DIM + ni * 16 + l16] = lv * h;
        }
      }
    }
  }
  __syncthreads();
  if (wn == 1) {
#pragma unroll
    for (int mi = 0; mi < 4; ++mi) {
#pragma unroll
      for (int reg = 0; reg < 4; ++reg) {
        int row = wm * 64 + mi * 16 + quad * 4 + reg;
        float lv = lam[(size_t)(gm0 + row) * 64 + rule];
#pragma unroll
        for (int ni = 0; ni < 4; ++ni) {
          float z = acc[mi][ni][reg] + bv[ni];
          float h = 1.f / (1.f + __expf(-z));
          ypart[row * O_DIM + ni * 16 + l16] += lv * h;
        }
      }
    }
  }
  __syncthreads();

  // write 128x64 fp32 slice, fully coalesced (2048 float4 by 256 threads)
  float* pdst = partial + (size_t)blockIdx.x * SO + (size_t)gm0 * O_DIM;
#pragma unroll
  for (int j = 0; j < 8; ++j) {
    int q = j * 256 + t;
    ((float4*)pdst)[q] = ((const float4*)ypart)[q];
  }
}

// ---------------------------------------------------------------- final reduce over 32 N-tiles
__global__ __launch_bounds__(256) void reduce_kernel(const float* __restrict__ partial,
                                                     float* __restrict__ Y) {
  int i = blockIdx.x * 256 + threadIdx.x;
  float s = 0.f;
#pragma unroll
  for (int c = 0; c < 32; ++c) s += partial[(size_t)c * SO + i];
  Y[i] = s;
}

extern "C" void kernel_launch(void* const* d_in, const int* in_sizes, int n_in,
                              void* d_out, int out_size, void* d_ws, size_t ws_size,
                              hipStream_t stream) {
  const float* X = (const float*)d_in[0];     // [8192,1024]
  const float* W = (const float*)d_in[1];     // [4096,1024]
  const float* b = (const float*)d_in[2];     // [4096]
  const float* lam = (const float*)d_in[3];   // [8192,64]
  float* Y = (float*)d_out;                   // [8192,64]

  unsigned short* Xb = (unsigned short*)d_ws;                       // 16 MB
  unsigned short* Wb = Xb + (size_t)S_DIM * K_DIM;                  // 8 MB
  float* partial = (float*)(Wb + (size_t)RO_DIM * K_DIM);           // 32 slices * 2 MB = 67 MB

  int nCast = ((S_DIM + RO_DIM) * K_DIM / 4) / 256;  // 12288 blocks
  cast_kernel<<<nCast, 256, 0, stream>>>(X, W, Xb, Wb);

  dim3 g(RO_DIM / 128, S_DIM / 128);  // (32, 64)
  gemm_kernel<<<g, 256, 0, stream>>>(Xb, Wb, b, lam, partial);

  reduce_kernel<<<SO / 256, 256, 0, stream>>>(partial, Y);
}